// Round 6
// baseline (134.665 us; speedup 1.0000x reference)
//
#include <hip/hip_runtime.h>
#include <math.h>

#define H 512
#define NN 8
#define NC 5

// ---------- math helpers (saturation-safe fast transcendentals) ----------
__device__ __forceinline__ float reluf(float x) { return x > 0.f ? x : 0.f; }

__device__ __forceinline__ float sigf(float x) {
    // robust: x<<0 -> expf(-x)=inf -> 0 ; x>>0 -> expf(-x)=0 -> 1
    return 1.0f / (1.0f + __expf(-x));
}

__device__ __forceinline__ float tanh_fast(float x) {
    // tanh(|x|) = 1 - 2/(exp(2|x|)+1); exp overflow -> exactly 1. No NaN.
    float ax = fabsf(x);
    float e = __expf(2.0f * ax);
    float t = 1.0f - 2.0f / (e + 1.0f);
    return copysignf(t, x);
}

// combine for one output column k; r1/r2 point at the cell's [8][H] raw
// (pre-relu) dot results.
__device__ __forceinline__ float combine_fn(const float* __restrict__ r1,
                                            const float* __restrict__ r2,
                                            int k) {
    float t[8];
#pragma unroll
    for (int n = 0; n < 8; ++n)
        t[n] = reluf(r1[n * H + k]) + reluf(r2[n * H + k]);
    float m0 = reluf(t[0]) + sigf(t[3]);
    float m1 = sigf(t[1]) + tanh_fast(t[2]);
    float m2 = sigf(t[4]) * tanh_fast(t[5]);
    float m3 = sigf(t[6]) * reluf(t[7]);
    float m4 = sigf(m1) + tanh_fast(m2);
    float m5 = tanh_fast(m0) * tanh_fast(m3);
    float m6 = tanh_fast(m4) * tanh_fast(m5);
    return tanh_fast(m6);
}

struct Ptrs { const float* x[6]; };  // a,b,c,d,e,state_init

// ---------- Kernel A: all 40 x@W1 products + cell-0 h@W2 (48 matvecs) ----
// grid = 48 matrices * 8 h-chunks(64 rows) = 384 blocks, 256 threads.
// Each thread owns 2 consecutive k (float2), streams 64 rows; atomicAdd
// partial dot into raw buffers (pre-zeroed). Reads are fully coalesced
// (block reads whole 2KB rows).
__global__ __launch_bounds__(256) void k_mm_all(Ptrs P,
                                                const float* __restrict__ W1,
                                                const float* __restrict__ W2,
                                                float* __restrict__ raw1,
                                                float* __restrict__ raw2) {
    int bid = blockIdx.x;
    int c = bid & 7;    // h-chunk (64 rows)
    int m = bid >> 3;   // matrix id 0..47
    const float* x;
    const float* W;
    float* dst;
    if (m < 40) {
        int i = m >> 3;                       // cell
        x = P.x[i];
        W = W1 + (size_t)m * H * H;           // W1[i][n]
        dst = raw1 + m * H;
    } else {
        int n = m - 40;
        x = P.x[5];                           // state_init
        W = W2 + (size_t)n * H * H;           // W2[0][n]
        dst = raw2 + n * H;                   // raw2 cell-0 region
    }
    __shared__ float sx[64];
    int t = threadIdx.x;
    if (t < 64) sx[t] = x[c * 64 + t];
    __syncthreads();

    int k0 = t * 2;
    const float* Wp = W + (size_t)(c * 64) * H + k0;
    float ax = 0.f, ay = 0.f;
#pragma unroll
    for (int h = 0; h < 64; ++h) {
        float2 w = *(const float2*)(Wp + (size_t)h * H);
        ax = fmaf(sx[h], w.x, ax);
        ay = fmaf(sx[h], w.y, ay);
    }
    atomicAdd(dst + k0, ax);
    atomicAdd(dst + k0 + 1, ay);
}

// ---------- Kernel B: one sequential cell's h@W2 (cell = 1..4) -----------
// grid = 8 nodes * 32 h-chunks(16 rows) = 256 blocks, 256 threads.
// Threads 0..15 recompute the previous cell's combine for this chunk's 16
// h-rows (reads 8*2 raw values each, L2-hot). Then stream the W2 chunk.
__global__ __launch_bounds__(256) void k_cell(int cell,
                                              const float* __restrict__ W2,
                                              const float* __restrict__ raw1,
                                              float* __restrict__ raw2) {
    int bid = blockIdx.x;
    int c = bid & 31;   // h-chunk of 16 rows
    int n = bid >> 5;   // node
    int t = threadIdx.x;

    __shared__ float sh[16];
    const float* r1p = raw1 + (size_t)(cell - 1) * NN * H;
    const float* r2p = raw2 + (size_t)(cell - 1) * NN * H;
    if (t < 16) sh[t] = combine_fn(r1p, r2p, c * 16 + t);
    __syncthreads();

    const float* W = W2 + (size_t)(cell * 8 + n) * H * H + (size_t)(c * 16) * H;
    int k0 = t * 2;
    float ax = 0.f, ay = 0.f;
#pragma unroll
    for (int h = 0; h < 16; ++h) {
        float2 w = *(const float2*)(W + (size_t)h * H + k0);
        ax = fmaf(sh[h], w.x, ax);
        ay = fmaf(sh[h], w.y, ay);
    }
    float* dst = raw2 + (size_t)(cell * NN + n) * H + k0;
    atomicAdd(dst, ax);
    atomicAdd(dst + 1, ay);
}

// ---------- Kernel F: final combine -> output ----------------------------
__global__ __launch_bounds__(256) void k_final(const float* __restrict__ raw1,
                                               const float* __restrict__ raw2,
                                               float* __restrict__ out) {
    int k = blockIdx.x * 256 + threadIdx.x;
    if (k < H)
        out[k] = combine_fn(raw1 + (size_t)4 * NN * H,
                            raw2 + (size_t)4 * NN * H, k);
}

extern "C" void kernel_launch(void* const* d_in, const int* in_sizes, int n_in,
                              void* d_out, int out_size, void* d_ws, size_t ws_size,
                              hipStream_t stream) {
    const float* a  = (const float*)d_in[0];
    const float* b  = (const float*)d_in[1];
    const float* cc = (const float*)d_in[2];
    const float* dd = (const float*)d_in[3];
    const float* e  = (const float*)d_in[4];
    const float* st = (const float*)d_in[5];
    const float* W1 = (const float*)d_in[6];
    const float* W2 = (const float*)d_in[7];
    float* out = (float*)d_out;

    float* ws = (float*)d_ws;
    float* raw1 = ws;                   // [5][8][512] pre-relu x@W1
    float* raw2 = ws + NC * NN * H;     // [5][8][512] pre-relu h@W2

    // zero the atomic accumulators (ws is poisoned before every launch)
    hipMemsetAsync(d_ws, 0, (size_t)2 * NC * NN * H * sizeof(float), stream);

    Ptrs P;
    P.x[0] = a; P.x[1] = b; P.x[2] = cc; P.x[3] = dd; P.x[4] = e; P.x[5] = st;

    k_mm_all<<<dim3(384), dim3(256), 0, stream>>>(P, W1, W2, raw1, raw2);
    for (int cell = 1; cell < NC; ++cell)
        k_cell<<<dim3(256), dim3(256), 0, stream>>>(cell, W2, raw1, raw2);
    k_final<<<dim3(2), dim3(256), 0, stream>>>(raw1, raw2, out);
}